// Round 10
// baseline (207.767 us; speedup 1.0000x reference)
//
#include <hip/hip_runtime.h>
#include <hip/hip_bf16.h>
#include <stdint.h>

// Problem dims
#define T_TOK 2048
#define HD    1024
#define NE    8
#define FD    1408
#define F2D   2816
#define HP    1056     // xbf row pitch (bf16)
#define W2P   1056     // w2bf row pitch (bf16)
#define OP    1056     // o row pitch (f32)

// GEMM tiling
#define BM 128
#define BK 32
#define MAXMT 40
#define MAXSLOTS 5120
#define FC1_NT 22      // FD/64
#define FC2_NT 16      // HD/64
#define FC1_NWG (FC1_NT * MAXMT)   // 880
#define FC2_NWG (FC2_NT * MAXMT)   // 640
#define FC1_CHUNK 110
#define FC2_CHUNK 80

// prep partition: streaming cvt only (no transpose) + router
#define PREP_W1 5632
#define PREP_W2 2816
#define PREP_ROUTER 512
#define PREP_NWG (PREP_W1 + PREP_W2 + PREP_ROUTER)

typedef __attribute__((ext_vector_type(8))) short bf16x8;
typedef __attribute__((ext_vector_type(4))) float f32x4;
typedef __attribute__((ext_vector_type(2))) int i32x2;

__device__ __forceinline__ unsigned short f2bf(float f) {
  unsigned int u = __float_as_uint(f);
  u += 0x7FFFu + ((u >> 16) & 1u);   // RNE
  return (unsigned short)(u >> 16);
}

#define GLL16(gp, lp) __builtin_amdgcn_global_load_lds( \
    (const __attribute__((address_space(1))) void*)(gp), \
    (__attribute__((address_space(3))) void*)(lp), 16, 0, 0)

#define LDS_OFF(p) ((unsigned)(uintptr_t)(__attribute__((address_space(3))) const unsigned short*)(p))

// Issue two transpose reads (one B-fragment: k=8g..8g+3 via tile, +4..7 via
// offset:512). Early-clobber so dests can never alias the addr register.
// NO unpacking here -- raw destinations only.
__device__ __forceinline__ void tr_issue(unsigned a, i32x2& lo, i32x2& hi) {
  asm volatile("ds_read_b64_tr_b16 %0, %2\n\t"
               "ds_read_b64_tr_b16 %1, %2 offset:512"
               : "=&v"(lo), "=&v"(hi)
               : "v"(a)
               : "memory");
}
// Unpack AFTER the explicit lgkmcnt(0)+sched_barrier at the call site.
__device__ __forceinline__ bf16x8 tr_pack(i32x2 lo, i32x2 hi) {
  union { i32x2 v; short s[4]; } a, b;
  a.v = lo; b.v = hi;
  bf16x8 f;
  f[0] = a.s[0]; f[1] = a.s[1]; f[2] = a.s[2]; f[3] = a.s[3];
  f[4] = b.s[0]; f[5] = b.s[1]; f[6] = b.s[2]; f[7] = b.s[3];
  return f;
}

// ---------------------------------------------------------------------------
// Prep: streaming f32->bf16 cvt of w1 (native [H][2F]) and w2 (re-pitch to
// [F][1056]) -- contiguous reads AND writes -- plus router.
// ---------------------------------------------------------------------------
__global__ __launch_bounds__(256) void k_prep(
    const float* __restrict__ x,  const float* __restrict__ rw,
    const float* __restrict__ w1, const float* __restrict__ w2,
    unsigned short* __restrict__ w1bf, unsigned short* __restrict__ w2bf,
    unsigned short* __restrict__ xbf, int* __restrict__ ctrl,
    int* __restrict__ tok_e, float* __restrict__ tok_p)
{
  const int b = blockIdx.x;
  if (b < PREP_W1) {
    const size_t base4 = (size_t)b * 1024 + threadIdx.x;
#pragma unroll
    for (int i = 0; i < 4; ++i) {
      const size_t idx4 = base4 + i * 256;
      float4 v = reinterpret_cast<const float4*>(w1)[idx4];
      ushort4 u;
      u.x = f2bf(v.x); u.y = f2bf(v.y); u.z = f2bf(v.z); u.w = f2bf(v.w);
      reinterpret_cast<ushort4*>(w1bf)[idx4] = u;
    }
    return;
  }
  if (b < PREP_W1 + PREP_W2) {
    const int bb = b - PREP_W1;
#pragma unroll
    for (int i = 0; i < 4; ++i) {
      const int idx = i * 256 + threadIdx.x;
      const int row = bb * 4 + (idx >> 8);
      const int c4 = idx & 255;
      float4 v = *reinterpret_cast<const float4*>(&w2[(size_t)row * HD + c4 * 4]);
      ushort4 u;
      u.x = f2bf(v.x); u.y = f2bf(v.y); u.z = f2bf(v.z); u.w = f2bf(v.w);
      *reinterpret_cast<ushort4*>(&w2bf[(size_t)row * W2P + c4 * 4]) = u;
    }
    return;
  }

  // ---- router: one wave per token ----
  const int lane = threadIdx.x & 63;
  const int t = (b - PREP_W1 - PREP_W2) * 4 + (threadIdx.x >> 6);
  const float* xr = x + (size_t)t * HD;

  float part[8];
#pragma unroll
  for (int e = 0; e < 8; ++e) part[e] = 0.f;

#pragma unroll
  for (int i = 0; i < 16; ++i) {
    const int h = i * 64 + lane;
    const float xv = xr[h];
    xbf[(size_t)t * HP + h] = f2bf(xv);
    const float4* rwr = reinterpret_cast<const float4*>(rw + (size_t)h * 8);
    float4 a = rwr[0], bb = rwr[1];
    part[0] += xv * a.x; part[1] += xv * a.y; part[2] += xv * a.z; part[3] += xv * a.w;
    part[4] += xv * bb.x; part[5] += xv * bb.y; part[6] += xv * bb.z; part[7] += xv * bb.w;
  }
#pragma unroll
  for (int e = 0; e < 8; ++e) {
    float v = part[e];
#pragma unroll
    for (int d = 32; d; d >>= 1) v += __shfl_xor(v, d, 64);
    part[e] = v;
  }
  float m = part[0];
#pragma unroll
  for (int e = 1; e < 8; ++e) m = fmaxf(m, part[e]);
  float p[8], s = 0.f;
#pragma unroll
  for (int e = 0; e < 8; ++e) { p[e] = __expf(part[e] - m); s += p[e]; }
  const float inv = 1.f / s;
#pragma unroll
  for (int e = 0; e < 8; ++e) p[e] *= inv;

  int e0 = 0; float p0 = p[0];
#pragma unroll
  for (int e = 1; e < 8; ++e) if (p[e] > p0) { p0 = p[e]; e0 = e; }
  int e1 = -1; float p1 = -1.f;
#pragma unroll
  for (int e = 0; e < 8; ++e) if (e != e0 && p[e] > p1) { p1 = p[e]; e1 = e; }

  if (lane == 0) {
    tok_e[t * 2 + 0] = e0; tok_e[t * 2 + 1] = e1;
    tok_p[t * 2 + 0] = p0; tok_p[t * 2 + 1] = p1;
    atomicAdd(&ctrl[e0], 1);
    atomicAdd(&ctrl[e1], 1);
  }
}

// ---------------------------------------------------------------------------
// Offsets (unchanged).
// ---------------------------------------------------------------------------
__global__ __launch_bounds__(256) void k_offsets(
    int* __restrict__ ctrl, int* __restrict__ stok, float* __restrict__ sp,
    int* __restrict__ widmt1, int* __restrict__ widmt2)
{
  __shared__ int soff[8], scnt[8], sFirst[8], sNmt[8], sTake[8];
  __shared__ int sSpill;
  if (threadIdx.x == 0) {
    int o = 0, nm = 0, spill = 0;
    for (int e = 0; e < 8; ++e) {
      ctrl[16 + e] = o; soff[e] = o; scnt[e] = ctrl[e];
      const int n = ctrl[e];
      const int nmt = (n + BM - 1) / BM;
      sFirst[e] = nm; sNmt[e] = nmt; sTake[e] = nmt < 5 ? nmt : 5;
      if (nmt > 5) spill = 1;
      for (int j = 0; j < nmt; ++j) { ctrl[24 + nm] = e; ctrl[64 + nm] = o + j * BM; ++nm; }
      o += nmt * BM;
    }
    for (int i = nm; i < MAXMT; ++i) ctrl[24 + i] = -1;
    sSpill = spill;
  }
  __syncthreads();
  for (int i = threadIdx.x; i < FC1_NWG; i += 256) {
    const int e = i / FC1_CHUNK, r = i % FC1_CHUNK;
    const int j = r / FC1_NT, n = r % FC1_NT;
    widmt1[i] = (j < sTake[e]) ? (sFirst[e] + j) * 32 + n : -1;
  }
  for (int i = threadIdx.x; i < FC2_NWG; i += 256) {
    const int e = i / FC2_CHUNK, r = i % FC2_CHUNK;
    const int j = r / FC2_NT, n = r % FC2_NT;
    widmt2[i] = (j < sTake[e]) ? (sFirst[e] + j) * 32 + n : -1;
  }
  __syncthreads();
  if (sSpill && threadIdx.x == 0) {
    int cur = 0;
    for (int e = 0; e < 8; ++e)
      for (int j = 5; j < sNmt[e]; ++j)
        for (int n = 0; n < FC1_NT; ++n) {
          while (widmt1[cur] != -1) ++cur;
          widmt1[cur] = (sFirst[e] + j) * 32 + n;
        }
    cur = 0;
    for (int e = 0; e < 8; ++e)
      for (int j = 5; j < sNmt[e]; ++j)
        for (int n = 0; n < FC2_NT; ++n) {
          while (widmt2[cur] != -1) ++cur;
          widmt2[cur] = (sFirst[e] + j) * 32 + n;
        }
  }
  for (int e = 0; e < 8; ++e) {
    const int n = scnt[e], o = soff[e];
    const int padEnd = (n + BM - 1) / BM * BM;
    for (int j = n + (int)threadIdx.x; j < padEnd; j += 256) {
      stok[o + j] = 0; sp[o + j] = 0.f;
    }
  }
}

// ---------------------------------------------------------------------------
// Scatter (unchanged).
// ---------------------------------------------------------------------------
__global__ __launch_bounds__(256) void k_scatter(
    int* __restrict__ ctrl, const int* __restrict__ tok_e,
    const float* __restrict__ tok_p, int* __restrict__ stok,
    float* __restrict__ sp, int* __restrict__ tslot)
{
  const int t = blockIdx.x * 256 + threadIdx.x;
#pragma unroll
  for (int k = 0; k < 2; ++k) {
    const int e = tok_e[t * 2 + k];
    const float pp = tok_p[t * 2 + k];
    const int pos = atomicAdd(&ctrl[8 + e], 1);
    const int slot = ctrl[16 + e] + pos;
    stok[slot] = t; sp[slot] = pp;
    tslot[t * 2 + k] = slot;
  }
}

// ---------------------------------------------------------------------------
// fc1: y = X[slots] @ w1[e] (gate|up), fused silu(y1)*y2*p -> bf16 g.
// Native-layout B, subtiled LDS [k/4][n/16][4][16], ds_read_b64_tr_b16
// fragments (issue-all -> wait -> unpack). r5 pipeline/schedule.
// ---------------------------------------------------------------------------
__global__ __launch_bounds__(256) void k_fc1(
    const unsigned short* __restrict__ xbf,   // [T][HP] bf16
    const unsigned short* __restrict__ w1bf,  // [E][H][2F] bf16 (native)
    const int* __restrict__ ctrl,
    const int* __restrict__ stok,
    const float* __restrict__ sp,
    const int* __restrict__ widmt1,
    unsigned short* __restrict__ g)           // [MAXSLOTS][F] bf16
{
  const int bid = blockIdx.x;
  const int wid = (bid & 7) * FC1_CHUNK + (bid >> 3);
  const int packed = widmt1[wid];
  if (packed < 0) return;
  const int mt = packed >> 5;
  const int e = ctrl[24 + mt];
  const int rowbase = ctrl[64 + mt];
  const int n0 = (packed & 31) * 64;

  __shared__ unsigned short sA[3][BM * BK];   // 8 KB each
  __shared__ unsigned short sB1[3][64 * BK];  // 4 KB each (subtiled)
  __shared__ unsigned short sB2[3][64 * BK];

  const int tid = threadIdx.x;
  const int lane = tid & 63;
  const int wave = tid >> 6;
  const int wm = wave >> 1, wn = wave & 1;

  // A staging (proven): pre-swizzled source chunk.
  const int schunk = (lane & 3) ^ ((lane >> 3) & 3);
  const unsigned short* aSrc[2];
#pragma unroll
  for (int t4 = 0; t4 < 2; ++t4) {
    const int row = (t4 * 4 + wave) * 16 + (lane >> 2);
    const int tok = stok[rowbase + row];
    aSrc[t4] = xbf + (size_t)tok * HP + schunk * 8;
  }

  // B staging: per-lane global source = decode of lane's linear LDS slot in
  // the subtiled layout. k = 8w + 4*(l>>5) + ((l>>1)&3), n = 16*((l>>3)&3) + 8*(l&1).
  const int kdec = wave * 8 + ((lane >> 5) << 2) + ((lane >> 1) & 3);
  const int ndec = ((lane >> 3) & 3) * 16 + (lane & 1) * 8;
  const unsigned short* b1Src = w1bf + ((size_t)e * HD + kdec) * F2D + n0 + ndec;
  const unsigned short* b2Src = b1Src + FD;

  // A fragment LDS offsets (XOR-swizzled, conflict-free)
  const int c = lane >> 4;
  int aoff[4];
#pragma unroll
  for (int m = 0; m < 4; ++m) {
    const int row = wm * 64 + m * 16 + (lane & 15);
    aoff[m] = row * 32 + ((c ^ ((row >> 1) & 3)) << 3);
  }
  // tr-read byte offsets for the two n-fragments
  const unsigned trlane = (lane & 15) * 8 + (lane >> 4) * 1024;
  unsigned trb[2];
#pragma unroll
  for (int n = 0; n < 2; ++n) trb[n] = trlane + (wn * 2 + n) * 128;
  const unsigned b1base = LDS_OFF(&sB1[0][0]);
  const unsigned b2base = LDS_OFF(&sB2[0][0]);

  const f32x4 zero = {0.f, 0.f, 0.f, 0.f};
  f32x4 acc1[4][2], acc2[4][2];
#pragma unroll
  for (int m = 0; m < 4; ++m)
#pragma unroll
    for (int n = 0; n < 2; ++n) { acc1[m][n] = zero; acc2[m][n] = zero; }

  auto STAGE = [&](int buf, int kt) {
    const size_t kadd = (size_t)kt * BK;
#pragma unroll
    for (int t4 = 0; t4 < 2; ++t4)
      GLL16(aSrc[t4] + kadd, &sA[buf][(t4 * 4 + wave) * 512]);
    const size_t bkadd = (size_t)kt * BK * F2D;
    GLL16(b1Src + bkadd, &sB1[buf][wave * 512]);
    GLL16(b2Src + bkadd, &sB2[buf][wave * 512]);
  };

  const int NSTEP = HD / BK;   // 32
  STAGE(0, 0);
  STAGE(1, 1);
  int bsel = 0;
  for (int t = 0; t < NSTEP; ++t) {
    if (t < NSTEP - 2) { asm volatile("s_waitcnt vmcnt(4)" ::: "memory"); }
    else               { asm volatile("s_waitcnt vmcnt(0)" ::: "memory"); }
    __builtin_amdgcn_s_barrier();
    __builtin_amdgcn_sched_barrier(0);
    if (t + 2 < NSTEP) {
      int bnext = bsel + 2; if (bnext >= 3) bnext -= 3;
      STAGE(bnext, t + 2);
    }
    bf16x8 af[4];
#pragma unroll
    for (int m = 0; m < 4; ++m)
      af[m] = *(const bf16x8*)&sA[bsel][aoff[m]];
    // issue all 8 tr reads (raw dests), then one wait, then unpack
    i32x2 q1lo[2], q1hi[2], q2lo[2], q2hi[2];
#pragma unroll
    for (int n = 0; n < 2; ++n) {
      tr_issue(b1base + bsel * 4096 + trb[n], q1lo[n], q1hi[n]);
      tr_issue(b2base + bsel * 4096 + trb[n], q2lo[n], q2hi[n]);
    }
    asm volatile("s_waitcnt lgkmcnt(0)" ::: "memory");
    __builtin_amdgcn_sched_barrier(0);
    bf16x8 b1f[2], b2f[2];
#pragma unroll
    for (int n = 0; n < 2; ++n) {
      b1f[n] = tr_pack(q1lo[n], q1hi[n]);
      b2f[n] = tr_pack(q2lo[n], q2hi[n]);
    }
    __builtin_amdgcn_s_setprio(1);
#pragma unroll
    for (int m = 0; m < 4; ++m)
#pragma unroll
      for (int n = 0; n < 2; ++n) {
        acc1[m][n] = __builtin_amdgcn_mfma_f32_16x16x32_bf16(af[m], b1f[n], acc1[m][n], 0, 0, 0);
        acc2[m][n] = __builtin_amdgcn_mfma_f32_16x16x32_bf16(af[m], b2f[n], acc2[m][n], 0, 0, 0);
      }
    __builtin_amdgcn_s_setprio(0);
    bsel = bsel + 1 == 3 ? 0 : bsel + 1;
  }

  float prv[4][4];
#pragma unroll
  for (int m = 0; m < 4; ++m)
#pragma unroll
    for (int r = 0; r < 4; ++r)
      prv[m][r] = sp[rowbase + wm * 64 + m * 16 + (lane >> 4) * 4 + r];

#pragma unroll
  for (int m = 0; m < 4; ++m) {
    const int rb = rowbase + wm * 64 + m * 16 + (lane >> 4) * 4;
#pragma unroll
    for (int n = 0; n < 2; ++n) {
      const int col = n0 + wn * 32 + n * 16 + (lane & 15);
#pragma unroll
      for (int r = 0; r < 4; ++r) {
        const float y1 = acc1[m][n][r];
        const float y2 = acc2[m][n][r];
        const float gv = y1 / (1.f + __expf(-y1)) * y2 * prv[m][r];
        g[(size_t)(rb + r) * FD + col] = f2bf(gv);
      }
    }
  }
}

// ---------------------------------------------------------------------------
// fc2: o[slot] = g[slot] @ w2[e] -- native-layout B + tr-read fragments.
// ---------------------------------------------------------------------------
__global__ __launch_bounds__(256) void k_fc2(
    const unsigned short* __restrict__ g,     // [MAXSLOTS][F] bf16
    const unsigned short* __restrict__ w2bf,  // [E][F][W2P] bf16 (native)
    const int* __restrict__ ctrl,
    const int* __restrict__ widmt2,
    float* __restrict__ o)                    // [MAXSLOTS][OP] f32
{
  const int bid = blockIdx.x;
  const int wid = (bid & 7) * FC2_CHUNK + (bid >> 3);
  const int packed = widmt2[wid];
  if (packed < 0) return;
  const int mt = packed >> 5;
  const int e = ctrl[24 + mt];
  const int rowbase = ctrl[64 + mt];
  const int n0 = (packed & 31) * 64;

  __shared__ unsigned short sA[3][BM * BK];   // 8 KB each
  __shared__ unsigned short sB[3][64 * BK];   // 4 KB each (subtiled)

  const int tid = threadIdx.x;
  const int lane = tid & 63;
  const int wave = tid >> 6;
  const int wm = wave >> 1, wn = wave & 1;

  const int schunk = (lane & 3) ^ ((lane >> 3) & 3);
  const unsigned short* aSrc[2];
#pragma unroll
  for (int t4 = 0; t4 < 2; ++t4) {
    const int row = (t4 * 4 + wave) * 16 + (lane >> 2);
    aSrc[t4] = g + (size_t)(rowbase + row) * FD + schunk * 8;
  }

  const int kdec = wave * 8 + ((lane >> 5) << 2) + ((lane >> 1) & 3);
  const int ndec = ((lane >> 3) & 3) * 16 + (lane & 1) * 8;
  const unsigned short* bSrc = w2bf + ((size_t)e * FD + kdec) * W2P + n0 + ndec;

  const int c = lane >> 4;
  int aoff[4];
#pragma unroll
  for (int m = 0; m < 4; ++m) {
    const int row = wm * 64 + m * 16 + (lane & 15);
    aoff[m] = row * 32 + ((c ^ ((row >> 1) & 3)) << 3);
  }
  const unsigned trlane = (lane & 15) * 8 + (lane >> 4) * 1024;
  unsigned trb[2];
#pragma unroll
  for (int n = 0; n < 2; ++n) trb[n] = trlane + (wn * 2 + n) * 128;
  const unsigned bbase = LDS_OFF(&sB[0][0]);

  const f32x4 zero = {0.f, 0.f, 0.f, 0.f};
  f32x4 acc[4][2];
#pragma unroll
  for (int m = 0; m < 4; ++m)
#pragma unroll
    for (int n = 0; n < 2; ++n) acc[m][n] = zero;

  auto STAGE = [&](int buf, int kt) {
    const size_t kadd = (size_t)kt * BK;
#pragma unroll
    for (int t4 = 0; t4 < 2; ++t4)
      GLL16(aSrc[t4] + kadd, &sA[buf][(t4 * 4 + wave) * 512]);
    const size_t bkadd = (size_t)kt * BK * W2P;
    GLL16(bSrc + bkadd, &sB[buf][wave * 512]);
  };

  const int NSTEP = FD / BK;   // 44
  STAGE(0, 0);
  STAGE(1, 1);
  int bsel = 0;
  for (int t = 0; t < NSTEP; ++t) {
    if (t < NSTEP - 2) { asm volatile("s_waitcnt vmcnt(3)" ::: "memory"); }
    else               { asm volatile("s_waitcnt vmcnt(0)" ::: "memory"); }
    __builtin_amdgcn_s_barrier();
    __builtin_amdgcn_sched_barrier(0);
    if (t + 2 < NSTEP) {
      int bnext = bsel + 2; if (bnext >= 3) bnext -= 3;
      STAGE(bnext, t + 2);
    }
    bf16x8 af[4];
#pragma unroll
    for (int m = 0; m < 4; ++m)
      af[m] = *(const bf16x8*)&sA[bsel][aoff[m]];
    i32x2 qlo[2], qhi[2];
#pragma unroll
    for (int n = 0; n < 2; ++n)
      tr_issue(bbase + bsel * 4096 + trb[n], qlo[n], qhi[n]);
    asm volatile("s_waitcnt lgkmcnt(0)" ::: "memory");
    __builtin_amdgcn_sched_barrier(0);
    bf16x8 bf[2];
#pragma unroll
    for (int n = 0; n < 2; ++n)
      bf[n] = tr_pack(qlo[n], qhi[n]);
    __builtin_amdgcn_s_setprio(1);
#pragma unroll
    for (int m = 0; m < 4; ++m)
#pragma unroll
      for (int n = 0; n < 2; ++n)
        acc[m][n] = __builtin_amdgcn_mfma_f32_16x16x32_bf16(af[m], bf[n], acc[m][n], 0, 0, 0);
    __builtin_amdgcn_s_setprio(0);
    bsel = bsel + 1 == 3 ? 0 : bsel + 1;
  }

#pragma unroll
  for (int m = 0; m < 4; ++m) {
    const int rb = rowbase + wm * 64 + m * 16 + (lane >> 4) * 4;
#pragma unroll
    for (int n = 0; n < 2; ++n) {
      const int col = n0 + wn * 32 + n * 16 + (lane & 15);
#pragma unroll
      for (int r = 0; r < 4; ++r)
        o[(size_t)(rb + r) * OP + col] = acc[m][n][r];
    }
  }
}

// ---------------------------------------------------------------------------
// Combine (unchanged).
// ---------------------------------------------------------------------------
__global__ __launch_bounds__(256) void k_combine(
    const float* __restrict__ o, const int* __restrict__ tslot,
    float* __restrict__ out)
{
  const int t = blockIdx.x;
  const int c4 = threadIdx.x;
  const int sA = tslot[t * 2], sB = tslot[t * 2 + 1];
  const float4 a = reinterpret_cast<const float4*>(o + (size_t)sA * OP)[c4];
  const float4 b = reinterpret_cast<const float4*>(o + (size_t)sB * OP)[c4];
  float4 r;
  r.x = a.x + b.x; r.y = a.y + b.y; r.z = a.z + b.z; r.w = a.w + b.w;
  reinterpret_cast<float4*>(out)[(size_t)t * 256 + c4] = r;
}

// ---------------------------------------------------------------------------
extern "C" void kernel_launch(void* const* d_in, const int* in_sizes, int n_in,
                              void* d_out, int out_size, void* d_ws, size_t ws_size,
                              hipStream_t stream)
{
  const float* x  = (const float*)d_in[0];   // [2048,1,1024]
  const float* rw = (const float*)d_in[1];   // [1024,8]
  const float* w1 = (const float*)d_in[2];   // [8,1024,2816]
  const float* w2 = (const float*)d_in[3];   // [8,1408,1024]
  float* out = (float*)d_out;
  char* ws = (char*)d_ws;

  // ws layout (bytes)
  int*   ctrl   = (int*)(ws + 0);
  int*   tok_e  = (int*)(ws + 1024);
  float* tok_p  = (float*)(ws + 17408);
  int*   stok   = (int*)(ws + 33792);
  float* sp     = (float*)(ws + 54272);
  int*   tslot  = (int*)(ws + 74752);
  int*   widmt1 = (int*)(ws + 91136);
  int*   widmt2 = (int*)(ws + 94656);
  unsigned short* xbf  = (unsigned short*)(ws + 97280);      // [T][HP]      4.33 MB
  unsigned short* w1bf = (unsigned short*)(ws + 4422656);    // [E][H][2F]   46.1 MB
  unsigned short* w2bf = (unsigned short*)(ws + 50560000);   // [E][F][W2P]  23.8 MB
  unsigned short* g    = (unsigned short*)(ws + 74349568);   // [SLOTS][F]   14.5 MB
  // o aliases w1bf (dead after fc1; rewritten by next replay's k_prep).
  float* o = (float*)(ws + 4422656);                         // [SLOTS][OP]  21.6 MB

  hipMemsetAsync(ws, 0, 1024, stream);

  k_prep<<<PREP_NWG, 256, 0, stream>>>(x, rw, w1, w2, w1bf, w2bf, xbf, ctrl, tok_e, tok_p);
  k_offsets<<<1, 256, 0, stream>>>(ctrl, stok, sp, widmt1, widmt2);
  k_scatter<<<T_TOK / 256, 256, 0, stream>>>(ctrl, tok_e, tok_p, stok, sp, tslot);
  k_fc1<<<FC1_NWG, 256, 0, stream>>>(xbf, w1bf, ctrl, stok, sp, widmt1, g);
  k_fc2<<<FC2_NWG, 256, 0, stream>>>(g, w2bf, ctrl, widmt2, o);
  k_combine<<<T_TOK, 256, 0, stream>>>(o, tslot, out);
}